// Round 1
// baseline (382.498 us; speedup 1.0000x reference)
//
#include <hip/hip_runtime.h>

// Problem constants
#define DM   1024
#define NHQ  16
#define NKVH 4
#define HDIM 64
#define TTT  64
#define SSS  256
#define NBB  2
#define MROWS 32768   // NBB*SSS*TTT
#define NQKV 1536     // 1024 + 256 + 256

using short8 = __attribute__((ext_vector_type(8))) short;
using f32x4  = __attribute__((ext_vector_type(4))) float;

__device__ __forceinline__ short f2bf(float f) {
  union { float f; unsigned u; } v; v.f = f;
  unsigned r = v.u + 0x7fffu + ((v.u >> 16) & 1u);
  return (short)(r >> 16);
}

__device__ __forceinline__ f32x4 mfma16(short8 a, short8 b, f32x4 c) {
  return __builtin_amdgcn_mfma_f32_16x16x32_bf16(a, b, c, 0, 0, 0);
}

__device__ __forceinline__ void gload_lds16(const void* g, void* l) {
  __builtin_amdgcn_global_load_lds(
      (const __attribute__((address_space(1))) void*)g,
      (__attribute__((address_space(3))) void*)l, 16, 0, 0);
}

// ---------------------------------------------------------------
// Kernel 0a: x (B,T,S,D) f32 -> xb[(b*S+s)*T + t][D] bf16
// ---------------------------------------------------------------
__global__ __launch_bounds__(256) void k_xconv(const float* __restrict__ x,
                                               short* __restrict__ xb) {
  int r = blockIdx.x;            // n*64 + t
  int n = r >> 6, t = r & 63;
  int b = n >> 8, s = n & 255;
  const float4* src = (const float4*)(x + ((size_t)((b * TTT + t) * SSS + s)) * DM);
  short4* dst = (short4*)(xb + (size_t)r * DM);
  float4 v = src[threadIdx.x];
  short4 o;
  o.x = f2bf(v.x); o.y = f2bf(v.y); o.z = f2bf(v.z); o.w = f2bf(v.w);
  dst[threadIdx.x] = o;
}

// ---------------------------------------------------------------
// Kernel 0b: transpose weight (1024 x cols) f32 -> wt[cols x 1024] bf16
// ---------------------------------------------------------------
__global__ __launch_bounds__(256) void k_wt(const float* __restrict__ w,
                                            short* __restrict__ wt, int cols) {
  __shared__ float tile[32][33];
  int ctiles = cols >> 5;
  int tj = blockIdx.x % ctiles;    // col tile of src
  int td = blockIdx.x / ctiles;    // row tile of src
  int lx = threadIdx.x & 31, ly = threadIdx.x >> 5;
  #pragma unroll
  for (int rr = 0; rr < 32; rr += 8)
    tile[rr + ly][lx] = w[(size_t)(td * 32 + rr + ly) * cols + tj * 32 + lx];
  __syncthreads();
  #pragma unroll
  for (int rr = 0; rr < 32; rr += 8)
    wt[(size_t)(tj * 32 + rr + ly) * 1024 + td * 32 + lx] = f2bf(tile[lx][rr + ly]);
}

// ---------------------------------------------------------------
// Shared GEMM core: C_tile(128x128) = A(128 x 1024 rows of K) * B^T(128 x 1024)
// A row-major M x K (bf16), B given N x K (bf16). 4 waves, 16x16x32 MFMA.
// ---------------------------------------------------------------
__device__ __forceinline__ void gemm_k1024(const short* __restrict__ Ab,
                                           const short* __restrict__ Bb,
                                           short* As, short* Bs,
                                           int tid, int lane, int wr, int wc,
                                           f32x4 (&acc)[4][4]) {
  const int ln15 = lane & 15, lhi = lane >> 4;
  for (int kt = 0; kt < 1024; kt += 64) {
    #pragma unroll
    for (int i = 0; i < 4; ++i) {
      int c = i * 256 + tid;
      int row = c >> 3, c8 = c & 7;
      gload_lds16(Ab + (size_t)row * 1024 + kt + c8 * 8, As + c * 8);
      gload_lds16(Bb + (size_t)row * 1024 + kt + c8 * 8, Bs + c * 8);
    }
    __syncthreads();
    #pragma unroll
    for (int kk = 0; kk < 2; ++kk) {
      int ko = kk * 32 + lhi * 8;
      short8 a[4], b[4];
      #pragma unroll
      for (int m = 0; m < 4; ++m)
        a[m] = *(const short8*)(As + (wr * 64 + m * 16 + ln15) * 64 + ko);
      #pragma unroll
      for (int n = 0; n < 4; ++n)
        b[n] = *(const short8*)(Bs + (wc * 64 + n * 16 + ln15) * 64 + ko);
      #pragma unroll
      for (int m = 0; m < 4; ++m)
        #pragma unroll
        for (int n = 0; n < 4; ++n)
          acc[m][n] = mfma16(a[m], b[n], acc[m][n]);
    }
    __syncthreads();
  }
}

// ---------------------------------------------------------------
// Kernel 1: QKV projection + RMSNorm + RoPE  (fused epilogue)
// ---------------------------------------------------------------
__global__ __launch_bounds__(256) void k_qkv(
    const short* __restrict__ xb, const short* __restrict__ wt,
    const float* __restrict__ qscale, const float* __restrict__ kscale,
    const float* __restrict__ rcos, const float* __restrict__ rsin,
    short* __restrict__ qb, short* __restrict__ kb, short* __restrict__ vb) {
  __shared__ __align__(16) short As[128 * 64];
  __shared__ __align__(16) short Bs[128 * 64];
  int tn = blockIdx.x % 12, tm = blockIdx.x / 12;
  int tid = threadIdx.x, lane = tid & 63, wid = tid >> 6;
  int wr = wid >> 1, wc = wid & 1;
  f32x4 acc[4][4] = {};
  gemm_k1024(xb + (size_t)tm * 128 * 1024, wt + (size_t)tn * 128 * 1024,
             As, Bs, tid, lane, wr, wc, acc);
  int ln15 = lane & 15, lhi = lane >> 4;
  int j0 = tn * 128 + wc * 64;        // this wave covers one full head width
  int r0 = tm * 128 + wr * 64;
  if (j0 < 1280) {                    // q or k region: RMSNorm + RoPE
    const float* scale = (j0 < 1024) ? qscale : kscale;
    float sc[4];
    #pragma unroll
    for (int n = 0; n < 4; ++n) sc[n] = scale[n * 16 + ln15];
    #pragma unroll
    for (int m = 0; m < 4; ++m) {
      #pragma unroll
      for (int j = 0; j < 4; ++j) {
        float ss = 0.f;
        #pragma unroll
        for (int n = 0; n < 4; ++n) { float v = acc[m][n][j]; ss += v * v; }
        #pragma unroll
        for (int off = 8; off; off >>= 1) ss += __shfl_xor(ss, off, 64);
        float rms = rsqrtf(ss * (1.f / 64.f) + 1e-6f);
        int r = r0 + m * 16 + lhi * 4 + j;
        int t = r & 63;
        #pragma unroll
        for (int n = 0; n < 2; ++n) {
          int i = n * 16 + ln15;                 // 0..31 (first half)
          float cs = rcos[t * 32 + i], sn = rsin[t * 32 + i];
          float v1 = acc[m][n][j] * rms * sc[n];
          float v2 = acc[m][n + 2][j] * rms * sc[n + 2];
          float o1 = v1 * cs - v2 * sn;
          float o2 = v1 * sn + v2 * cs;
          if (j0 < 1024) {
            qb[(size_t)r * 1024 + j0 + i]      = f2bf(o1);
            qb[(size_t)r * 1024 + j0 + i + 32] = f2bf(o2);
          } else {
            int jk = j0 - 1024;
            kb[(size_t)r * 256 + jk + i]      = f2bf(o1);
            kb[(size_t)r * 256 + jk + i + 32] = f2bf(o2);
          }
        }
      }
    }
  } else {                            // v region: raw store
    int jv = j0 - 1280;
    #pragma unroll
    for (int m = 0; m < 4; ++m)
      #pragma unroll
      for (int n = 0; n < 4; ++n)
        #pragma unroll
        for (int j = 0; j < 4; ++j) {
          int r = r0 + m * 16 + lhi * 4 + j;
          vb[(size_t)r * 256 + jv + n * 16 + ln15] = f2bf(acc[m][n][j]);
        }
  }
}

// ---------------------------------------------------------------
// Kernel 2: attention per (n, h). T=64, hd=64. softcap + causal + softmax.
// ---------------------------------------------------------------
__global__ __launch_bounds__(256) void k_attn(const short* __restrict__ qb,
                                              const short* __restrict__ kb,
                                              const short* __restrict__ vb,
                                              short* __restrict__ ob) {
  __shared__ __align__(16) short Qs[64 * 72];
  __shared__ __align__(16) short Ks[64 * 72];
  __shared__ __align__(16) short Vt[64 * 72];   // transposed: [hd][t]
  __shared__ __align__(16) short Ps[64 * 72];
  int h = blockIdx.x & 15, n = blockIdx.x >> 4;
  int kvh = h >> 2;
  int tid = threadIdx.x, lane = tid & 63, wid = tid >> 6;
  // stage Q, K, V (V transposed)
  for (int c = tid; c < 512; c += 256) {
    int row = c >> 3, c8 = c & 7;
    *(uint4*)(&Qs[row * 72 + c8 * 8]) =
        *(const uint4*)(qb + (size_t)(n * 64 + row) * 1024 + h * 64 + c8 * 8);
    *(uint4*)(&Ks[row * 72 + c8 * 8]) =
        *(const uint4*)(kb + (size_t)(n * 64 + row) * 256 + kvh * 64 + c8 * 8);
    short8 vv = *(const short8*)(vb + (size_t)(n * 64 + row) * 256 + kvh * 64 + c8 * 8);
    #pragma unroll
    for (int e = 0; e < 8; ++e) Vt[(c8 * 8 + e) * 72 + row] = vv[e];
  }
  __syncthreads();
  int ln15 = lane & 15, lhi = lane >> 4;
  // scores: wave wid computes rows [wid*16, wid*16+16)
  f32x4 accs[4] = {};
  #pragma unroll
  for (int kk = 0; kk < 2; ++kk) {
    int ko = kk * 32 + lhi * 8;
    short8 aq = *(const short8*)(&Qs[(wid * 16 + ln15) * 72 + ko]);
    #pragma unroll
    for (int nn = 0; nn < 4; ++nn) {
      short8 bk = *(const short8*)(&Ks[(nn * 16 + ln15) * 72 + ko]);
      accs[nn] = mfma16(aq, bk, accs[nn]);
    }
  }
  // softcap + causal + softmax (row = 16-lane group)
  int rowloc = wid * 16 + lhi * 4;
  float p[4][4];
  #pragma unroll
  for (int j = 0; j < 4; ++j) {
    int row = rowloc + j;
    float m = -3e38f;
    #pragma unroll
    for (int nn = 0; nn < 4; ++nn) {
      float s = accs[nn][j] * 0.125f;          // / sqrt(64)
      s = 50.f * tanhf(s * 0.02f);             // softcap
      int col = nn * 16 + ln15;
      s = (col <= row) ? s : -1e30f;           // causal
      p[nn][j] = s;
      m = fmaxf(m, s);
    }
    #pragma unroll
    for (int off = 8; off; off >>= 1) m = fmaxf(m, __shfl_xor(m, off, 64));
    float sum = 0.f;
    #pragma unroll
    for (int nn = 0; nn < 4; ++nn) {
      float e = __expf(p[nn][j] - m);
      p[nn][j] = e; sum += e;
    }
    #pragma unroll
    for (int off = 8; off; off >>= 1) sum += __shfl_xor(sum, off, 64);
    float inv = 1.f / sum;
    #pragma unroll
    for (int nn = 0; nn < 4; ++nn) p[nn][j] *= inv;
  }
  // P -> LDS (bf16)
  #pragma unroll
  for (int nn = 0; nn < 4; ++nn)
    #pragma unroll
    for (int j = 0; j < 4; ++j)
      Ps[(rowloc + j) * 72 + nn * 16 + ln15] = f2bf(p[nn][j]);
  __syncthreads();
  // O = P * V  (B-frags from transposed V)
  f32x4 acco[4] = {};
  #pragma unroll
  for (int kk = 0; kk < 2; ++kk) {
    int ko = kk * 32 + lhi * 8;
    short8 ap = *(const short8*)(&Ps[(wid * 16 + ln15) * 72 + ko]);
    #pragma unroll
    for (int nn = 0; nn < 4; ++nn) {
      short8 bv = *(const short8*)(&Vt[(nn * 16 + ln15) * 72 + ko]);
      acco[nn] = mfma16(ap, bv, acco[nn]);
    }
  }
  #pragma unroll
  for (int nn = 0; nn < 4; ++nn)
    #pragma unroll
    for (int j = 0; j < 4; ++j) {
      int t = rowloc + j;
      ob[(size_t)(n * 64 + t) * 1024 + h * 64 + nn * 16 + ln15] = f2bf(acco[nn][j]);
    }
}

// ---------------------------------------------------------------
// Kernel 3: output projection + scatter to (B,T,S,D) f32
// ---------------------------------------------------------------
__global__ __launch_bounds__(256) void k_out(const short* __restrict__ ab,
                                             const short* __restrict__ wt,
                                             float* __restrict__ out) {
  __shared__ __align__(16) short As[128 * 64];
  __shared__ __align__(16) short Bs[128 * 64];
  int tn = blockIdx.x & 7, tm = blockIdx.x >> 3;
  int tid = threadIdx.x, lane = tid & 63, wid = tid >> 6;
  int wr = wid >> 1, wc = wid & 1;
  f32x4 acc[4][4] = {};
  gemm_k1024(ab + (size_t)tm * 128 * 1024, wt + (size_t)tn * 128 * 1024,
             As, Bs, tid, lane, wr, wc, acc);
  int ln15 = lane & 15, lhi = lane >> 4;
  #pragma unroll
  for (int m = 0; m < 4; ++m)
    #pragma unroll
    for (int j = 0; j < 4; ++j) {
      int r = tm * 128 + wr * 64 + m * 16 + lhi * 4 + j;
      int nseq = r >> 6, t = r & 63;
      int b = nseq >> 8, s = nseq & 255;
      float* orow = out + ((size_t)((b * TTT + t) * SSS + s)) * DM + tn * 128 + wc * 64;
      #pragma unroll
      for (int n = 0; n < 4; ++n)
        orow[n * 16 + ln15] = acc[m][n][j];
    }
}

// ---------------------------------------------------------------
extern "C" void kernel_launch(void* const* d_in, const int* in_sizes, int n_in,
                              void* d_out, int out_size, void* d_ws, size_t ws_size,
                              hipStream_t stream) {
  const float* x  = (const float*)d_in[0];
  const float* wq = (const float*)d_in[1];
  const float* wk = (const float*)d_in[2];
  const float* wv = (const float*)d_in[3];
  const float* wo = (const float*)d_in[4];
  const float* qs = (const float*)d_in[5];
  const float* ks = (const float*)d_in[6];
  const float* rc = (const float*)d_in[7];
  const float* rs = (const float*)d_in[8];
  float* out = (float*)d_out;
  char* ws = (char*)d_ws;

  short* xb    = (short*)(ws);                      // 64 MiB (xt bf16); later aliased as attn-out
  short* wqkvT = (short*)(ws + 67108864);           // 3 MiB  (1536 x 1024)
  short* woT   = (short*)(ws + 70254592);           // 2 MiB  (1024 x 1024)
  short* qb    = (short*)(ws + 72351744);           // 64 MiB
  short* kb    = (short*)(ws + 139460608);          // 16 MiB
  short* vb    = (short*)(ws + 156237824);          // 16 MiB  (end: 173,015,040)
  short* ob    = xb;                                // alias: xb dead after k_qkv

  k_xconv<<<MROWS, 256, 0, stream>>>(x, xb);
  k_wt<<<1024, 256, 0, stream>>>(wq, wqkvT, 1024);
  k_wt<<<256, 256, 0, stream>>>(wk, wqkvT + (size_t)1024 * 1024, 256);
  k_wt<<<256, 256, 0, stream>>>(wv, wqkvT + (size_t)1280 * 1024, 256);
  k_wt<<<1024, 256, 0, stream>>>(wo, woT, 1024);
  k_qkv<<<256 * 12, 256, 0, stream>>>(xb, wqkvT, qs, ks, rc, rs, qb, kb, vb);
  k_attn<<<512 * 16, 256, 0, stream>>>(qb, kb, vb, ob);
  k_out<<<256 * 8, 256, 0, stream>>>(ob, woT, out);
}

// Round 2
// 354.544 us; speedup vs baseline: 1.0788x; 1.0788x over previous
//
#include <hip/hip_runtime.h>

// Problem constants
#define DM   1024
#define NHQ  16
#define NKVH 4
#define HDIM 64
#define TTT  64
#define SSS  256
#define NBB  2
#define MROWS 32768   // NBB*SSS*TTT

using short8 = __attribute__((ext_vector_type(8))) short;
using f32x4  = __attribute__((ext_vector_type(4))) float;

__device__ __forceinline__ short f2bf(float f) {
  union { float f; unsigned u; } v; v.f = f;
  unsigned r = v.u + 0x7fffu + ((v.u >> 16) & 1u);
  return (short)(r >> 16);
}

__device__ __forceinline__ f32x4 mfma16(short8 a, short8 b, f32x4 c) {
  return __builtin_amdgcn_mfma_f32_16x16x32_bf16(a, b, c, 0, 0, 0);
}

__device__ __forceinline__ void gload_lds16(const void* g, void* l) {
  __builtin_amdgcn_global_load_lds(
      (const __attribute__((address_space(1))) void*)g,
      (__attribute__((address_space(3))) void*)l, 16, 0, 0);
}

// ---------------------------------------------------------------
// Kernel 0a: x (B,T,S,D) f32 -> xb[(b*S+s)*T + t][D] bf16
// ---------------------------------------------------------------
__global__ __launch_bounds__(256) void k_xconv(const float* __restrict__ x,
                                               short* __restrict__ xb) {
  int r = blockIdx.x;            // n*64 + t
  int n = r >> 6, t = r & 63;
  int b = n >> 8, s = n & 255;
  const float4* src = (const float4*)(x + ((size_t)((b * TTT + t) * SSS + s)) * DM);
  short4* dst = (short4*)(xb + (size_t)r * DM);
  float4 v = src[threadIdx.x];
  short4 o;
  o.x = f2bf(v.x); o.y = f2bf(v.y); o.z = f2bf(v.z); o.w = f2bf(v.w);
  dst[threadIdx.x] = o;
}

// ---------------------------------------------------------------
// Kernel 0b: transpose weight (1024 x cols) f32 -> wt[cols x 1024] bf16
// ---------------------------------------------------------------
__global__ __launch_bounds__(256) void k_wt(const float* __restrict__ w,
                                            short* __restrict__ wt, int cols) {
  __shared__ float tile[32][33];
  int ctiles = cols >> 5;
  int tj = blockIdx.x % ctiles;    // col tile of src
  int td = blockIdx.x / ctiles;    // row tile of src
  int lx = threadIdx.x & 31, ly = threadIdx.x >> 5;
  #pragma unroll
  for (int rr = 0; rr < 32; rr += 8)
    tile[rr + ly][lx] = w[(size_t)(td * 32 + rr + ly) * cols + tj * 32 + lx];
  __syncthreads();
  #pragma unroll
  for (int rr = 0; rr < 32; rr += 8)
    wt[(size_t)(tj * 32 + rr + ly) * 1024 + td * 32 + lx] = f2bf(tile[lx][rr + ly]);
}

// ---------------------------------------------------------------
// 256x256-tile GEMM core, K=1024, BK=64, 8 waves (2M x 4N), 512 threads.
// Double-buffered LDS (128 KiB), 2-phase: STAGE(t+1) issued BEFORE compute(t),
// one vmcnt(0)+barrier per K-tile (via __syncthreads).
// acc[8][4]: wave output 128x64 at rows wr*128, cols wc*64.
// ---------------------------------------------------------------
#define GEMM256_BODY(Ab, Bb)                                                   \
  const int tid = threadIdx.x, lane = tid & 63, wid = tid >> 6;                \
  const int wr = wid >> 2, wc = wid & 3;                                       \
  const int ln15 = lane & 15, lhi = lane >> 4;                                 \
  f32x4 acc[8][4] = {};                                                        \
  auto STAGE = [&](short* dA, short* dB, int kt) {                             \
    _Pragma("unroll")                                                          \
    for (int rr = 0; rr < 4; ++rr) {                                           \
      int c = rr * 512 + tid;                                                  \
      int row = c >> 3, c8 = c & 7;                                            \
      gload_lds16(Ab + (size_t)row * 1024 + kt + c8 * 8, dA + c * 8);          \
      gload_lds16(Bb + (size_t)row * 1024 + kt + c8 * 8, dB + c * 8);          \
    }                                                                          \
  };                                                                           \
  auto COMPUTE = [&](const short* cA, const short* cB) {                       \
    _Pragma("unroll")                                                          \
    for (int kk = 0; kk < 2; ++kk) {                                           \
      const int ko = kk * 32 + lhi * 8;                                        \
      short8 a[8], b[4];                                                       \
      _Pragma("unroll")                                                        \
      for (int n = 0; n < 4; ++n)                                              \
        b[n] = *(const short8*)(cB + (wc * 64 + n * 16 + ln15) * 64 + ko);     \
      _Pragma("unroll")                                                        \
      for (int m = 0; m < 8; ++m)                                              \
        a[m] = *(const short8*)(cA + (wr * 128 + m * 16 + ln15) * 64 + ko);    \
      _Pragma("unroll")                                                        \
      for (int m = 0; m < 8; ++m)                                              \
        _Pragma("unroll")                                                      \
        for (int n = 0; n < 4; ++n) acc[m][n] = mfma16(a[m], b[n], acc[m][n]); \
    }                                                                          \
  };                                                                           \
  STAGE(sm, sm + 16384, 0);                                                    \
  __syncthreads();                                                             \
  for (int t = 0; t < 15; ++t) {                                               \
    short* cA = (t & 1) ? sm + 32768 : sm;                                     \
    short* cB = (t & 1) ? sm + 49152 : sm + 16384;                             \
    short* nA = (t & 1) ? sm : sm + 32768;                                     \
    short* nB = (t & 1) ? sm + 16384 : sm + 49152;                             \
    STAGE(nA, nB, (t + 1) * 64);                                               \
    COMPUTE(cA, cB);                                                           \
    __syncthreads();                                                           \
  }                                                                            \
  COMPUTE(sm + 32768, sm + 49152);                                             \
  __syncthreads();

// ---------------------------------------------------------------
// Kernel 1: QKV projection + RMSNorm + RoPE, LDS-staged vectorized stores
// grid 768 = 128 tm x 6 tn
// ---------------------------------------------------------------
__global__ __launch_bounds__(512) void k_qkv(
    const short* __restrict__ xb, const short* __restrict__ wt,
    const float* __restrict__ qscale, const float* __restrict__ kscale,
    const float* __restrict__ rcos, const float* __restrict__ rsin,
    short* __restrict__ qb, short* __restrict__ kb, short* __restrict__ vb) {
  __shared__ __align__(16) short sm[65536];   // 128 KiB
  const int bid = blockIdx.x;
  const int swz = (bid & 7) * 96 + (bid >> 3);   // bijective, 768 % 8 == 0
  const int tn = swz % 6, tm = swz / 6;
  const short* Ab = xb + (size_t)tm * 256 * 1024;
  const short* Bb = wt + (size_t)tn * 256 * 1024;
  GEMM256_BODY(Ab, Bb)

  // ---- epilogue: compute into LDS bf16 [256][256], then coalesced stores
  short* ot = sm;
  if (tn < 5) {                       // q (tn 0-3) or k (tn 4): RMSNorm + RoPE
    const float* scale = (tn < 4) ? qscale : kscale;
    float sc[4];
    #pragma unroll
    for (int n = 0; n < 4; ++n) sc[n] = scale[n * 16 + ln15];
    #pragma unroll
    for (int m = 0; m < 8; ++m) {
      #pragma unroll
      for (int j = 0; j < 4; ++j) {
        float ss = 0.f;
        #pragma unroll
        for (int n = 0; n < 4; ++n) { float v = acc[m][n][j]; ss += v * v; }
        #pragma unroll
        for (int off = 8; off; off >>= 1) ss += __shfl_xor(ss, off, 64);
        float rms = rsqrtf(ss * (1.f / 64.f) + 1e-6f);
        int rl = wr * 128 + m * 16 + lhi * 4 + j;   // local row in tile
        int t = (tm * 256 + rl) & 63;
        #pragma unroll
        for (int n = 0; n < 2; ++n) {
          int i = n * 16 + ln15;                    // 0..31 (first half)
          float cs = rcos[t * 32 + i], sn = rsin[t * 32 + i];
          float v1 = acc[m][n][j] * rms * sc[n];
          float v2 = acc[m][n + 2][j] * rms * sc[n + 2];
          ot[rl * 256 + wc * 64 + i]      = f2bf(v1 * cs - v2 * sn);
          ot[rl * 256 + wc * 64 + i + 32] = f2bf(v1 * sn + v2 * cs);
        }
      }
    }
  } else {                            // v: raw
    #pragma unroll
    for (int m = 0; m < 8; ++m)
      #pragma unroll
      for (int n = 0; n < 4; ++n)
        #pragma unroll
        for (int j = 0; j < 4; ++j) {
          int rl = wr * 128 + m * 16 + lhi * 4 + j;
          ot[rl * 256 + wc * 64 + n * 16 + ln15] = f2bf(acc[m][n][j]);
        }
  }
  __syncthreads();
  // store: 256 rows x 512B; each thread one 256B half-row (16 x uint4)
  {
    int row = tid >> 1, half = tid & 1;
    int r = tm * 256 + row;
    const uint4* src = (const uint4*)(ot + row * 256 + half * 128);
    short* dst;
    if (tn < 4)       dst = qb + (size_t)r * 1024 + tn * 256 + half * 128;
    else if (tn == 4) dst = kb + (size_t)r * 256 + half * 128;
    else              dst = vb + (size_t)r * 256 + half * 128;
    uint4* d4 = (uint4*)dst;
    #pragma unroll
    for (int i = 0; i < 16; ++i) d4[i] = src[i];
  }
}

// ---------------------------------------------------------------
// Kernel 2: attention per (n, h). T=64, hd=64. softcap + causal + softmax.
// ---------------------------------------------------------------
__global__ __launch_bounds__(256) void k_attn(const short* __restrict__ qb,
                                              const short* __restrict__ kb,
                                              const short* __restrict__ vb,
                                              short* __restrict__ ob) {
  __shared__ __align__(16) short Qs[64 * 72];
  __shared__ __align__(16) short Ks[64 * 72];
  __shared__ __align__(16) short Vt[64 * 72];   // transposed: [hd][t]
  __shared__ __align__(16) short Ps[64 * 72];
  int h = blockIdx.x & 15, n = blockIdx.x >> 4;
  int kvh = h >> 2;
  int tid = threadIdx.x, lane = tid & 63, wid = tid >> 6;
  for (int c = tid; c < 512; c += 256) {
    int row = c >> 3, c8 = c & 7;
    *(uint4*)(&Qs[row * 72 + c8 * 8]) =
        *(const uint4*)(qb + (size_t)(n * 64 + row) * 1024 + h * 64 + c8 * 8);
    *(uint4*)(&Ks[row * 72 + c8 * 8]) =
        *(const uint4*)(kb + (size_t)(n * 64 + row) * 256 + kvh * 64 + c8 * 8);
    short8 vv = *(const short8*)(vb + (size_t)(n * 64 + row) * 256 + kvh * 64 + c8 * 8);
    #pragma unroll
    for (int e = 0; e < 8; ++e) Vt[(c8 * 8 + e) * 72 + row] = vv[e];
  }
  __syncthreads();
  int ln15 = lane & 15, lhi = lane >> 4;
  f32x4 accs[4] = {};
  #pragma unroll
  for (int kk = 0; kk < 2; ++kk) {
    int ko = kk * 32 + lhi * 8;
    short8 aq = *(const short8*)(&Qs[(wid * 16 + ln15) * 72 + ko]);
    #pragma unroll
    for (int nn = 0; nn < 4; ++nn) {
      short8 bk = *(const short8*)(&Ks[(nn * 16 + ln15) * 72 + ko]);
      accs[nn] = mfma16(aq, bk, accs[nn]);
    }
  }
  int rowloc = wid * 16 + lhi * 4;
  float p[4][4];
  #pragma unroll
  for (int j = 0; j < 4; ++j) {
    int row = rowloc + j;
    float m = -3e38f;
    #pragma unroll
    for (int nn = 0; nn < 4; ++nn) {
      float s = accs[nn][j] * 0.125f;
      s = 50.f * tanhf(s * 0.02f);
      int col = nn * 16 + ln15;
      s = (col <= row) ? s : -1e30f;
      p[nn][j] = s;
      m = fmaxf(m, s);
    }
    #pragma unroll
    for (int off = 8; off; off >>= 1) m = fmaxf(m, __shfl_xor(m, off, 64));
    float sum = 0.f;
    #pragma unroll
    for (int nn = 0; nn < 4; ++nn) {
      float e = __expf(p[nn][j] - m);
      p[nn][j] = e; sum += e;
    }
    #pragma unroll
    for (int off = 8; off; off >>= 1) sum += __shfl_xor(sum, off, 64);
    float inv = 1.f / sum;
    #pragma unroll
    for (int nn = 0; nn < 4; ++nn) p[nn][j] *= inv;
  }
  #pragma unroll
  for (int nn = 0; nn < 4; ++nn)
    #pragma unroll
    for (int j = 0; j < 4; ++j)
      Ps[(rowloc + j) * 72 + nn * 16 + ln15] = f2bf(p[nn][j]);
  __syncthreads();
  f32x4 acco[4] = {};
  #pragma unroll
  for (int kk = 0; kk < 2; ++kk) {
    int ko = kk * 32 + lhi * 8;
    short8 ap = *(const short8*)(&Ps[(wid * 16 + ln15) * 72 + ko]);
    #pragma unroll
    for (int nn = 0; nn < 4; ++nn) {
      short8 bv = *(const short8*)(&Vt[(nn * 16 + ln15) * 72 + ko]);
      acco[nn] = mfma16(ap, bv, acco[nn]);
    }
  }
  #pragma unroll
  for (int nn = 0; nn < 4; ++nn)
    #pragma unroll
    for (int j = 0; j < 4; ++j) {
      int t = rowloc + j;
      ob[(size_t)(n * 64 + t) * 1024 + h * 64 + nn * 16 + ln15] = f2bf(acco[nn][j]);
    }
}

// ---------------------------------------------------------------
// Kernel 3: output projection + scatter to (B,T,S,D) f32
// grid 512 = 128 tm x 4 tn; LDS-staged f32 stores (two 128-row chunks)
// ---------------------------------------------------------------
__global__ __launch_bounds__(512) void k_out(const short* __restrict__ ab,
                                             const short* __restrict__ wt,
                                             float* __restrict__ out) {
  __shared__ __align__(16) short sm[65536];   // 128 KiB
  const int bid = blockIdx.x;
  const int swz = (bid & 7) * 64 + (bid >> 3);   // bijective, 512 % 8 == 0
  const int tn = swz & 3, tm = swz >> 2;
  const short* Ab = ab + (size_t)tm * 256 * 1024;
  const short* Bb = wt + (size_t)tn * 256 * 1024;
  GEMM256_BODY(Ab, Bb)

  // ---- epilogue: two 128-row chunks via LDS f32 [128][256]
  float* of = (float*)sm;
  #pragma unroll
  for (int ch = 0; ch < 2; ++ch) {
    if (wr == ch) {
      #pragma unroll
      for (int m = 0; m < 8; ++m)
        #pragma unroll
        for (int n = 0; n < 4; ++n)
          #pragma unroll
          for (int j = 0; j < 4; ++j)
            of[(m * 16 + lhi * 4 + j) * 256 + wc * 64 + n * 16 + ln15] = acc[m][n][j];
    }
    __syncthreads();
    {
      int row = tid >> 2, q4 = tid & 3;            // 128 rows x 4 quarter-rows
      int r = tm * 256 + ch * 128 + row;
      int nseq = r >> 6, t = r & 63;
      int b = nseq >> 8, s = nseq & 255;
      float* dst = out + ((size_t)((b * TTT + t) * SSS + s)) * DM + tn * 256 + q4 * 64;
      const float4* src = (const float4*)(of + row * 256 + q4 * 64);
      float4* d4 = (float4*)dst;
      #pragma unroll
      for (int i = 0; i < 16; ++i) d4[i] = src[i];
    }
    __syncthreads();
  }
}

// ---------------------------------------------------------------
extern "C" void kernel_launch(void* const* d_in, const int* in_sizes, int n_in,
                              void* d_out, int out_size, void* d_ws, size_t ws_size,
                              hipStream_t stream) {
  const float* x  = (const float*)d_in[0];
  const float* wq = (const float*)d_in[1];
  const float* wk = (const float*)d_in[2];
  const float* wv = (const float*)d_in[3];
  const float* wo = (const float*)d_in[4];
  const float* qs = (const float*)d_in[5];
  const float* ks = (const float*)d_in[6];
  const float* rc = (const float*)d_in[7];
  const float* rs = (const float*)d_in[8];
  float* out = (float*)d_out;
  char* ws = (char*)d_ws;

  short* xb    = (short*)(ws);                      // 64 MiB; later aliased as attn-out
  short* wqkvT = (short*)(ws + 67108864);           // 3 MiB  (1536 x 1024)
  short* woT   = (short*)(ws + 70254592);           // 2 MiB  (1024 x 1024)
  short* qb    = (short*)(ws + 72351744);           // 64 MiB
  short* kb    = (short*)(ws + 139460608);          // 16 MiB
  short* vb    = (short*)(ws + 156237824);          // 16 MiB
  short* ob    = xb;                                // alias: xb dead after k_qkv

  k_xconv<<<MROWS, 256, 0, stream>>>(x, xb);
  k_wt<<<1024, 256, 0, stream>>>(wq, wqkvT, 1024);
  k_wt<<<256, 256, 0, stream>>>(wk, wqkvT + (size_t)1024 * 1024, 256);
  k_wt<<<256, 256, 0, stream>>>(wv, wqkvT + (size_t)1280 * 1024, 256);
  k_wt<<<1024, 256, 0, stream>>>(wo, woT, 1024);
  k_qkv<<<768, 512, 0, stream>>>(xb, wqkvT, qs, ks, rc, rs, qb, kb, vb);
  k_attn<<<512 * 16, 256, 0, stream>>>(qb, kb, vb, ob);
  k_out<<<512, 512, 0, stream>>>(ob, woT, out);
}

// Round 3
// 341.895 us; speedup vs baseline: 1.1188x; 1.0370x over previous
//
#include <hip/hip_runtime.h>

// Problem constants
#define DM   1024
#define NHQ  16
#define NKVH 4
#define HDIM 64
#define TTT  64
#define SSS  256
#define NBB  2
#define MROWS 32768   // NBB*SSS*TTT

using short8 = __attribute__((ext_vector_type(8))) short;
using f32x4  = __attribute__((ext_vector_type(4))) float;

__device__ __forceinline__ short f2bf(float f) {
  union { float f; unsigned u; } v; v.f = f;
  unsigned r = v.u + 0x7fffu + ((v.u >> 16) & 1u);
  return (short)(r >> 16);
}

__device__ __forceinline__ f32x4 mfma16(short8 a, short8 b, f32x4 c) {
  return __builtin_amdgcn_mfma_f32_16x16x32_bf16(a, b, c, 0, 0, 0);
}

__device__ __forceinline__ void gload_lds16(const void* g, void* l) {
  __builtin_amdgcn_global_load_lds(
      (const __attribute__((address_space(1))) void*)g,
      (__attribute__((address_space(3))) void*)l, 16, 0, 0);
}

// ---------------------------------------------------------------
// Kernel 0a: x (B,T,S,D) f32 -> xb[(b*S+s)*T + t][D] bf16
// ---------------------------------------------------------------
__global__ __launch_bounds__(256) void k_xconv(const float* __restrict__ x,
                                               short* __restrict__ xb) {
  int r = blockIdx.x;            // n*64 + t
  int n = r >> 6, t = r & 63;
  int b = n >> 8, s = n & 255;
  const float4* src = (const float4*)(x + ((size_t)((b * TTT + t) * SSS + s)) * DM);
  short4* dst = (short4*)(xb + (size_t)r * DM);
  float4 v = src[threadIdx.x];
  short4 o;
  o.x = f2bf(v.x); o.y = f2bf(v.y); o.z = f2bf(v.z); o.w = f2bf(v.w);
  dst[threadIdx.x] = o;
}

// ---------------------------------------------------------------
// Kernel 0b: transpose weight (1024 x cols) f32 -> wt[cols x 1024] bf16
// ---------------------------------------------------------------
__global__ __launch_bounds__(256) void k_wt(const float* __restrict__ w,
                                            short* __restrict__ wt, int cols) {
  __shared__ float tile[32][33];
  int ctiles = cols >> 5;
  int tj = blockIdx.x % ctiles;    // col tile of src
  int td = blockIdx.x / ctiles;    // row tile of src
  int lx = threadIdx.x & 31, ly = threadIdx.x >> 5;
  #pragma unroll
  for (int rr = 0; rr < 32; rr += 8)
    tile[rr + ly][lx] = w[(size_t)(td * 32 + rr + ly) * cols + tj * 32 + lx];
  __syncthreads();
  #pragma unroll
  for (int rr = 0; rr < 32; rr += 8)
    wt[(size_t)(tj * 32 + rr + ly) * 1024 + td * 32 + lx] = f2bf(tile[lx][rr + ly]);
}

// ---------------------------------------------------------------
// 256x256 GEMM core, K=1024, BK=64, 8 waves (2Mx4N), 512 threads.
// 8-phase schedule (4 phases/K-tile, 2 K-tiles double-buffered):
//   counted vmcnt (never 0 in main loop), raw s_barrier, T2 XOR swizzle
//   (pre-swizzled global source + swizzled ds_read), T5 setprio on MFMA.
// LDS (shorts): buf0 A [0,16384) B [16384,32768); buf1 A [32768,...) B [49152,...)
// ---------------------------------------------------------------
#define GEMM256_8PH(Ab, Bb)                                                    \
  const int tid = threadIdx.x, lane = tid & 63, wid = tid >> 6;                \
  const int wr = wid >> 2, wc = wid & 3;                                       \
  const int ln15 = lane & 15, lhi = lane >> 4;                                 \
  const int rsw = ln15 & 7;                                                    \
  f32x4 acc[8][4] = {};                                                        \
  auto SHALF = [&](const short* gb, short* lb, int half, int kt) {             \
    _Pragma("unroll")                                                          \
    for (int i = 0; i < 2; ++i) {                                              \
      int c = i * 512 + tid;                                                   \
      int row = c >> 3, slot = c & 7;                                          \
      gload_lds16(gb + (size_t)(half * 128 + row) * 1024 + kt                  \
                     + ((slot ^ (row & 7)) << 3),                              \
                  lb + half * 8192 + c * 8);                                   \
    }                                                                          \
  };                                                                           \
  /* prologue: stage K-tiles 0 and 1 (16 loads/thread) */                      \
  SHALF(Ab, sm, 0, 0); SHALF(Ab, sm, 1, 0);                                    \
  SHALF(Bb, sm + 16384, 0, 0); SHALF(Bb, sm + 16384, 1, 0);                    \
  SHALF(Ab, sm + 32768, 0, 64); SHALF(Ab, sm + 32768, 1, 64);                  \
  SHALF(Bb, sm + 49152, 0, 64); SHALF(Bb, sm + 49152, 1, 64);                  \
  asm volatile("s_waitcnt vmcnt(8)" ::: "memory");                             \
  __builtin_amdgcn_s_barrier();                                                \
  for (int g = 0; g < 16; ++g) {                                               \
    short* cA = sm + (g & 1) * 32768;                                          \
    short* cB = cA + 16384;                                                    \
    short* nA = sm + ((g + 1) & 1) * 32768;                                    \
    const bool iA = (g > 0) && (g < 15);                                       \
    const bool iB = (g < 14);                                                  \
    short8 a[4], b0[4], b1[4];                                                 \
    /* ---- q0: b0(kk0)+a(m0-3,kk0); issue A-lo(g+1) ---- */                   \
    _Pragma("unroll")                                                          \
    for (int n = 0; n < 4; ++n)                                                \
      b0[n] = *(const short8*)(cB + (wc * 64 + n * 16 + ln15) * 64             \
                                  + ((lhi ^ rsw) << 3));                       \
    _Pragma("unroll")                                                          \
    for (int m = 0; m < 4; ++m)                                                \
      a[m] = *(const short8*)(cA + (wr * 128 + m * 16 + ln15) * 64             \
                                 + ((lhi ^ rsw) << 3));                        \
    if (iA) SHALF(Ab, nA, 0, (g + 1) * 64);                                    \
    __builtin_amdgcn_s_barrier();                                              \
    asm volatile("s_waitcnt lgkmcnt(0)" ::: "memory");                         \
    __builtin_amdgcn_s_setprio(1);                                             \
    _Pragma("unroll")                                                          \
    for (int m = 0; m < 4; ++m)                                                \
      _Pragma("unroll")                                                        \
      for (int n = 0; n < 4; ++n) acc[m][n] = mfma16(a[m], b0[n], acc[m][n]);  \
    __builtin_amdgcn_s_setprio(0);                                             \
    __builtin_amdgcn_s_barrier();                                              \
    /* ---- q1: a(m4-7,kk0); issue A-hi(g+1) ---- */                           \
    _Pragma("unroll")                                                          \
    for (int m = 0; m < 4; ++m)                                                \
      a[m] = *(const short8*)(cA + (wr * 128 + 64 + m * 16 + ln15) * 64        \
                                 + ((lhi ^ rsw) << 3));                        \
    if (iA) SHALF(Ab, nA, 1, (g + 1) * 64);                                    \
    __builtin_amdgcn_s_barrier();                                              \
    asm volatile("s_waitcnt lgkmcnt(0)" ::: "memory");                         \
    __builtin_amdgcn_s_setprio(1);                                             \
    _Pragma("unroll")                                                          \
    for (int m = 0; m < 4; ++m)                                                \
      _Pragma("unroll")                                                        \
      for (int n = 0; n < 4; ++n)                                              \
        acc[4 + m][n] = mfma16(a[m], b0[n], acc[4 + m][n]);                    \
    __builtin_amdgcn_s_setprio(0);                                             \
    __builtin_amdgcn_s_barrier();                                              \
    /* ---- q2: b1(kk1)+a(m0-3,kk1) ---- */                                    \
    _Pragma("unroll")                                                          \
    for (int n = 0; n < 4; ++n)                                                \
      b1[n] = *(const short8*)(cB + (wc * 64 + n * 16 + ln15) * 64             \
                                  + (((4 + lhi) ^ rsw) << 3));                 \
    _Pragma("unroll")                                                          \
    for (int m = 0; m < 4; ++m)                                                \
      a[m] = *(const short8*)(cA + (wr * 128 + m * 16 + ln15) * 64             \
                                 + (((4 + lhi) ^ rsw) << 3));                  \
    __builtin_amdgcn_s_barrier();                                              \
    asm volatile("s_waitcnt lgkmcnt(0)" ::: "memory");                         \
    __builtin_amdgcn_s_setprio(1);                                             \
    _Pragma("unroll")                                                          \
    for (int m = 0; m < 4; ++m)                                                \
      _Pragma("unroll")                                                        \
      for (int n = 0; n < 4; ++n) acc[m][n] = mfma16(a[m], b1[n], acc[m][n]);  \
    __builtin_amdgcn_s_setprio(0);                                             \
    __builtin_amdgcn_s_barrier();                                              \
    /* ---- q3: a(m4-7,kk1); issue B-lo/hi(g+2); vmcnt(4) ---- */              \
    _Pragma("unroll")                                                          \
    for (int m = 0; m < 4; ++m)                                                \
      a[m] = *(const short8*)(cA + (wr * 128 + 64 + m * 16 + ln15) * 64        \
                                 + (((4 + lhi) ^ rsw) << 3));                  \
    if (iB) { SHALF(Bb, cB, 0, (g + 2) * 64); SHALF(Bb, cB, 1, (g + 2) * 64); }\
    __builtin_amdgcn_s_barrier();                                              \
    asm volatile("s_waitcnt lgkmcnt(0)" ::: "memory");                         \
    __builtin_amdgcn_s_setprio(1);                                             \
    _Pragma("unroll")                                                          \
    for (int m = 0; m < 4; ++m)                                                \
      _Pragma("unroll")                                                        \
      for (int n = 0; n < 4; ++n)                                              \
        acc[4 + m][n] = mfma16(a[m], b1[n], acc[4 + m][n]);                    \
    __builtin_amdgcn_s_setprio(0);                                             \
    if (g < 14)       asm volatile("s_waitcnt vmcnt(4)" ::: "memory");         \
    else if (g == 14) asm volatile("s_waitcnt vmcnt(0)" ::: "memory");         \
    __builtin_amdgcn_s_barrier();                                              \
  }

// ---------------------------------------------------------------
// Kernel 1: QKV projection + RMSNorm + RoPE, LDS-staged vectorized stores
// grid 768 = 128 tm x 6 tn
// ---------------------------------------------------------------
__global__ __launch_bounds__(512, 2) void k_qkv(
    const short* __restrict__ xb, const short* __restrict__ wt,
    const float* __restrict__ qscale, const float* __restrict__ kscale,
    const float* __restrict__ rcos, const float* __restrict__ rsin,
    short* __restrict__ qb, short* __restrict__ kb, short* __restrict__ vb) {
  __shared__ __align__(16) short sm[65536];   // 128 KiB
  const int bid = blockIdx.x;
  const int swz = (bid & 7) * 96 + (bid >> 3);   // bijective, 768 % 8 == 0
  const int tn = swz % 6, tm = swz / 6;
  const short* Ab = xb + (size_t)tm * 256 * 1024;
  const short* Bb = wt + (size_t)tn * 256 * 1024;
  GEMM256_8PH(Ab, Bb)

  // ---- epilogue: compute into LDS bf16 [256][256], then coalesced stores
  short* ot = sm;
  if (tn < 5) {                       // q (tn 0-3) or k (tn 4): RMSNorm + RoPE
    const float* scale = (tn < 4) ? qscale : kscale;
    float sc[4];
    #pragma unroll
    for (int n = 0; n < 4; ++n) sc[n] = scale[n * 16 + ln15];
    #pragma unroll
    for (int m = 0; m < 8; ++m) {
      #pragma unroll
      for (int j = 0; j < 4; ++j) {
        float ss = 0.f;
        #pragma unroll
        for (int n = 0; n < 4; ++n) { float v = acc[m][n][j]; ss += v * v; }
        #pragma unroll
        for (int off = 8; off; off >>= 1) ss += __shfl_xor(ss, off, 64);
        float rms = rsqrtf(ss * (1.f / 64.f) + 1e-6f);
        int rl = wr * 128 + m * 16 + lhi * 4 + j;   // local row in tile
        int t = (tm * 256 + rl) & 63;
        #pragma unroll
        for (int n = 0; n < 2; ++n) {
          int i = n * 16 + ln15;                    // 0..31 (first half)
          float cs = rcos[t * 32 + i], sn = rsin[t * 32 + i];
          float v1 = acc[m][n][j] * rms * sc[n];
          float v2 = acc[m][n + 2][j] * rms * sc[n + 2];
          ot[rl * 256 + wc * 64 + i]      = f2bf(v1 * cs - v2 * sn);
          ot[rl * 256 + wc * 64 + i + 32] = f2bf(v1 * sn + v2 * cs);
        }
      }
    }
  } else {                            // v: raw
    #pragma unroll
    for (int m = 0; m < 8; ++m)
      #pragma unroll
      for (int n = 0; n < 4; ++n)
        #pragma unroll
        for (int j = 0; j < 4; ++j) {
          int rl = wr * 128 + m * 16 + lhi * 4 + j;
          ot[rl * 256 + wc * 64 + n * 16 + ln15] = f2bf(acc[m][n][j]);
        }
  }
  __syncthreads();
  // store: 256 rows x 512B; each thread one 256B half-row (16 x uint4)
  {
    int row = tid >> 1, half = tid & 1;
    int r = tm * 256 + row;
    const uint4* src = (const uint4*)(ot + row * 256 + half * 128);
    short* dst;
    if (tn < 4)       dst = qb + (size_t)r * 1024 + tn * 256 + half * 128;
    else if (tn == 4) dst = kb + (size_t)r * 256 + half * 128;
    else              dst = vb + (size_t)r * 256 + half * 128;
    uint4* d4 = (uint4*)dst;
    #pragma unroll
    for (int i = 0; i < 16; ++i) d4[i] = src[i];
  }
}

// ---------------------------------------------------------------
// Kernel 2: attention per (n, h). T=64, hd=64. softcap + causal + softmax.
// ---------------------------------------------------------------
__global__ __launch_bounds__(256) void k_attn(const short* __restrict__ qb,
                                              const short* __restrict__ kb,
                                              const short* __restrict__ vb,
                                              short* __restrict__ ob) {
  __shared__ __align__(16) short Qs[64 * 72];
  __shared__ __align__(16) short Ks[64 * 72];
  __shared__ __align__(16) short Vt[64 * 72];   // transposed: [hd][t]
  __shared__ __align__(16) short Ps[64 * 72];
  int h = blockIdx.x & 15, n = blockIdx.x >> 4;
  int kvh = h >> 2;
  int tid = threadIdx.x, lane = tid & 63, wid = tid >> 6;
  for (int c = tid; c < 512; c += 256) {
    int row = c >> 3, c8 = c & 7;
    *(uint4*)(&Qs[row * 72 + c8 * 8]) =
        *(const uint4*)(qb + (size_t)(n * 64 + row) * 1024 + h * 64 + c8 * 8);
    *(uint4*)(&Ks[row * 72 + c8 * 8]) =
        *(const uint4*)(kb + (size_t)(n * 64 + row) * 256 + kvh * 64 + c8 * 8);
    short8 vv = *(const short8*)(vb + (size_t)(n * 64 + row) * 256 + kvh * 64 + c8 * 8);
    #pragma unroll
    for (int e = 0; e < 8; ++e) Vt[(c8 * 8 + e) * 72 + row] = vv[e];
  }
  __syncthreads();
  int ln15 = lane & 15, lhi = lane >> 4;
  f32x4 accs[4] = {};
  #pragma unroll
  for (int kk = 0; kk < 2; ++kk) {
    int ko = kk * 32 + lhi * 8;
    short8 aq = *(const short8*)(&Qs[(wid * 16 + ln15) * 72 + ko]);
    #pragma unroll
    for (int nn = 0; nn < 4; ++nn) {
      short8 bk = *(const short8*)(&Ks[(nn * 16 + ln15) * 72 + ko]);
      accs[nn] = mfma16(aq, bk, accs[nn]);
    }
  }
  int rowloc = wid * 16 + lhi * 4;
  float p[4][4];
  #pragma unroll
  for (int j = 0; j < 4; ++j) {
    int row = rowloc + j;
    float m = -3e38f;
    #pragma unroll
    for (int nn = 0; nn < 4; ++nn) {
      float s = accs[nn][j] * 0.125f;
      s = 50.f * tanhf(s * 0.02f);
      int col = nn * 16 + ln15;
      s = (col <= row) ? s : -1e30f;
      p[nn][j] = s;
      m = fmaxf(m, s);
    }
    #pragma unroll
    for (int off = 8; off; off >>= 1) m = fmaxf(m, __shfl_xor(m, off, 64));
    float sum = 0.f;
    #pragma unroll
    for (int nn = 0; nn < 4; ++nn) {
      float e = __expf(p[nn][j] - m);
      p[nn][j] = e; sum += e;
    }
    #pragma unroll
    for (int off = 8; off; off >>= 1) sum += __shfl_xor(sum, off, 64);
    float inv = 1.f / sum;
    #pragma unroll
    for (int nn = 0; nn < 4; ++nn) p[nn][j] *= inv;
  }
  #pragma unroll
  for (int nn = 0; nn < 4; ++nn)
    #pragma unroll
    for (int j = 0; j < 4; ++j)
      Ps[(rowloc + j) * 72 + nn * 16 + ln15] = f2bf(p[nn][j]);
  __syncthreads();
  f32x4 acco[4] = {};
  #pragma unroll
  for (int kk = 0; kk < 2; ++kk) {
    int ko = kk * 32 + lhi * 8;
    short8 ap = *(const short8*)(&Ps[(wid * 16 + ln15) * 72 + ko]);
    #pragma unroll
    for (int nn = 0; nn < 4; ++nn) {
      short8 bv = *(const short8*)(&Vt[(nn * 16 + ln15) * 72 + ko]);
      acco[nn] = mfma16(ap, bv, acco[nn]);
    }
  }
  #pragma unroll
  for (int nn = 0; nn < 4; ++nn)
    #pragma unroll
    for (int j = 0; j < 4; ++j) {
      int t = rowloc + j;
      ob[(size_t)(n * 64 + t) * 1024 + h * 64 + nn * 16 + ln15] = f2bf(acco[nn][j]);
    }
}

// ---------------------------------------------------------------
// Kernel 3: output projection + scatter to (B,T,S,D) f32
// grid 512 = 128 tm x 4 tn; LDS-staged f32 stores (two 128-row chunks)
// ---------------------------------------------------------------
__global__ __launch_bounds__(512, 2) void k_out(const short* __restrict__ ab,
                                                const short* __restrict__ wt,
                                                float* __restrict__ out) {
  __shared__ __align__(16) short sm[65536];   // 128 KiB
  const int bid = blockIdx.x;
  const int swz = (bid & 7) * 64 + (bid >> 3);   // bijective, 512 % 8 == 0
  const int tn = swz & 3, tm = swz >> 2;
  const short* Ab = ab + (size_t)tm * 256 * 1024;
  const short* Bb = wt + (size_t)tn * 256 * 1024;
  GEMM256_8PH(Ab, Bb)

  // ---- epilogue: two 128-row chunks via LDS f32 [128][256]
  float* of = (float*)sm;
  #pragma unroll
  for (int ch = 0; ch < 2; ++ch) {
    if (wr == ch) {
      #pragma unroll
      for (int m = 0; m < 8; ++m)
        #pragma unroll
        for (int n = 0; n < 4; ++n)
          #pragma unroll
          for (int j = 0; j < 4; ++j)
            of[(m * 16 + lhi * 4 + j) * 256 + wc * 64 + n * 16 + ln15] = acc[m][n][j];
    }
    __syncthreads();
    {
      int row = tid >> 2, q4 = tid & 3;            // 128 rows x 4 quarter-rows
      int r = tm * 256 + ch * 128 + row;
      int nseq = r >> 6, t = r & 63;
      int b = nseq >> 8, s = nseq & 255;
      float* dst = out + ((size_t)((b * TTT + t) * SSS + s)) * DM + tn * 256 + q4 * 64;
      const float4* src = (const float4*)(of + row * 256 + q4 * 64);
      float4* d4 = (float4*)dst;
      #pragma unroll
      for (int i = 0; i < 16; ++i) d4[i] = src[i];
    }
    __syncthreads();
  }
}

// ---------------------------------------------------------------
extern "C" void kernel_launch(void* const* d_in, const int* in_sizes, int n_in,
                              void* d_out, int out_size, void* d_ws, size_t ws_size,
                              hipStream_t stream) {
  const float* x  = (const float*)d_in[0];
  const float* wq = (const float*)d_in[1];
  const float* wk = (const float*)d_in[2];
  const float* wv = (const float*)d_in[3];
  const float* wo = (const float*)d_in[4];
  const float* qs = (const float*)d_in[5];
  const float* ks = (const float*)d_in[6];
  const float* rc = (const float*)d_in[7];
  const float* rs = (const float*)d_in[8];
  float* out = (float*)d_out;
  char* ws = (char*)d_ws;

  short* xb    = (short*)(ws);                      // 64 MiB; later aliased as attn-out
  short* wqkvT = (short*)(ws + 67108864);           // 3 MiB  (1536 x 1024)
  short* woT   = (short*)(ws + 70254592);           // 2 MiB  (1024 x 1024)
  short* qb    = (short*)(ws + 72351744);           // 64 MiB
  short* kb    = (short*)(ws + 139460608);          // 16 MiB
  short* vb    = (short*)(ws + 156237824);          // 16 MiB
  short* ob    = xb;                                // alias: xb dead after k_qkv

  k_xconv<<<MROWS, 256, 0, stream>>>(x, xb);
  k_wt<<<1024, 256, 0, stream>>>(wq, wqkvT, 1024);
  k_wt<<<256, 256, 0, stream>>>(wk, wqkvT + (size_t)1024 * 1024, 256);
  k_wt<<<256, 256, 0, stream>>>(wv, wqkvT + (size_t)1280 * 1024, 256);
  k_wt<<<1024, 256, 0, stream>>>(wo, woT, 1024);
  k_qkv<<<768, 512, 0, stream>>>(xb, wqkvT, qs, ks, rc, rs, qb, kb, vb);
  k_attn<<<512 * 16, 256, 0, stream>>>(qb, kb, vb, ob);
  k_out<<<512, 512, 0, stream>>>(ob, woT, out);
}